// Round 7
// baseline (385.559 us; speedup 1.0000x reference)
//
#include <hip/hip_runtime.h>

// GCNConv: out[v] = isd[v] * sum_{(u->v)} x[u] * isd[u],  isd = rsqrt(max(outdeg,1))
// N=100000, E=1600000, D=128 fp32.
//
// R1->R2: bucketed gather killed the 800MB atomic write storm (866 -> 367us).
// R2->R5: three L2-locality fixes for build's bucket write amplification all
//   left WRITE_SIZE ~120-135MB -- structural scattered-atomic cost, build is
//   not BW-bound (1.2TB/s, VALU 4%). Reverted to best build (R4, 137us).
// R6: attack gather (~150-170us by subtraction): prescale xs=x*isd (kills
//   1.6M scattered isd loads), NT out-stores/bucket-loads (protect the x16
//   reused xs set in L2), unroll 8. R6 failed to COMPILE: HIP float4 is a
//   class, not a native vector -- __builtin_nontemporal_* needs
//   ext_vector_type. R7 = R6 with vfloat4 alias on the NT paths.

#define D_FEAT 128
#define CAP 32
#define NODES_PER_BLOCK 8   // gather: 256 threads, 32 lanes (float4) per node
#define NSLICES 8
#define BPS 512             // build blocks per slice

typedef float vfloat4 __attribute__((ext_vector_type(4)));

__global__ void build_kernel(const int* __restrict__ src, const int* __restrict__ dst,
                             int* __restrict__ deg, int* __restrict__ cnt,
                             int* __restrict__ bucket, int2* __restrict__ ovf,
                             int* __restrict__ novf, int E, int sliceSz) {
    int slice = blockIdx.x & (NSLICES - 1);
    int chunk = blockIdx.x >> 3;
    int lo = slice * sliceSz;
    int hi = lo + sliceSz;
    int chunkSz = (E + BPS - 1) / BPS;
    int beg = chunk * chunkSz;
    int end = min(E, beg + chunkSz);

    for (int i = beg + (int)threadIdx.x; i < end; i += blockDim.x) {
        int s = __builtin_nontemporal_load(src + i);
        int d = __builtin_nontemporal_load(dst + i);
        if (d >= lo && d < hi) {
            int slot = atomicAdd(&cnt[d], 1);
            if (slot < CAP) {
                bucket[d * CAP + slot] = s;
            } else {
                int o = atomicAdd(novf, 1);     // rare Poisson(16) tail
                ovf[o] = make_int2(s, d);
            }
        }
        if (s >= lo && s < hi) {
            atomicAdd(&deg[s], 1);
        }
    }
}

__global__ void isd_kernel(const int* __restrict__ deg, float* __restrict__ isd, int N) {
    int i = blockIdx.x * blockDim.x + threadIdx.x;
    if (i < N) isd[i] = rsqrtf(fmaxf((float)deg[i], 1.0f));
}

// xs[u][:] = x[u][:] * isd[u]  (one float4 per thread)
__global__ void prescale_kernel(const vfloat4* __restrict__ x4,
                                const float* __restrict__ isd,
                                vfloat4* __restrict__ xs4, int n4) {
    int i = blockIdx.x * blockDim.x + threadIdx.x;
    if (i >= n4) return;
    float w = isd[i >> 5];          // broadcast within each 32-lane row group
    vfloat4 v = x4[i] * w;
    __builtin_nontemporal_store(v, xs4 + i);   // write-once stream
}

// 8 nodes per 256-thread block; 32 threads per node, float4 per thread.
// xs rows are the ONLY cached traffic (reused x16 avg); bucket/cnt reads and
// out stores are non-temporal so they don't evict xs from L2.
__global__ __launch_bounds__(256) void gather_kernel(
        const vfloat4* __restrict__ xs4,
        const int* __restrict__ cnt,
        const int* __restrict__ bucket,
        const float* __restrict__ isd,
        vfloat4* __restrict__ out4, int N) {
    __shared__ int sh_idx[NODES_PER_BLOCK * CAP];
    int t = threadIdx.x;
    int node_slot = t >> 5;
    int lane = t & 31;
    int d = blockIdx.x * NODES_PER_BLOCK + node_slot;

    int c = 0;
    if (d < N) {
        c = min(__builtin_nontemporal_load(cnt + d), CAP);
        if (lane < c)
            sh_idx[node_slot * CAP + lane] =
                __builtin_nontemporal_load(bucket + d * CAP + lane);
    }
    __syncthreads();
    if (d >= N) return;

    vfloat4 acc = {0.f, 0.f, 0.f, 0.f};
    #pragma unroll 8
    for (int k = 0; k < c; ++k) {
        int s = sh_idx[node_slot * CAP + k];     // LDS broadcast
        acc += xs4[s * 32 + lane];               // 512B coalesced row gather
    }
    acc *= isd[d];
    __builtin_nontemporal_store(acc, out4 + d * 32 + lane);  // write-once
}

__global__ void overflow_kernel(const float* __restrict__ xs,
                                const float* __restrict__ isd,
                                const int2* __restrict__ ovf,
                                const int* __restrict__ novf,
                                float* __restrict__ out) {
    int n = *novf;
    for (int e = blockIdx.x; e < n; e += gridDim.x) {
        int2 sd = ovf[e];
        float coef = isd[sd.y];                  // xs already has isd[src]
        atomicAdd(&out[sd.y * D_FEAT + threadIdx.x],
                  xs[sd.x * D_FEAT + threadIdx.x] * coef);
    }
}

// ---- non-prescaled gather (used if ws can't hold xs) ----
__global__ __launch_bounds__(256) void gather_kernel_noprescale(
        const vfloat4* __restrict__ x4,
        const int* __restrict__ cnt,
        const int* __restrict__ bucket,
        const float* __restrict__ isd,
        vfloat4* __restrict__ out4, int N) {
    __shared__ int   sh_idx[NODES_PER_BLOCK * CAP];
    __shared__ float sh_w[NODES_PER_BLOCK * CAP];
    int t = threadIdx.x;
    int node_slot = t >> 5;
    int lane = t & 31;
    int d = blockIdx.x * NODES_PER_BLOCK + node_slot;

    int c = 0;
    if (d < N) {
        c = min(cnt[d], CAP);
        if (lane < c) {
            int s = bucket[d * CAP + lane];
            sh_idx[node_slot * CAP + lane] = s;
            sh_w[node_slot * CAP + lane] = isd[s];
        }
    }
    __syncthreads();
    if (d >= N) return;

    vfloat4 acc = {0.f, 0.f, 0.f, 0.f};
    #pragma unroll 8
    for (int k = 0; k < c; ++k) {
        int s   = sh_idx[node_slot * CAP + k];
        float w = sh_w[node_slot * CAP + k];
        acc += x4[s * 32 + lane] * w;
    }
    acc *= isd[d];
    __builtin_nontemporal_store(acc, out4 + d * 32 + lane);
}

__global__ void overflow_kernel_noprescale(const float* __restrict__ x,
                                           const float* __restrict__ isd,
                                           const int2* __restrict__ ovf,
                                           const int* __restrict__ novf,
                                           float* __restrict__ out) {
    int n = *novf;
    for (int e = blockIdx.x; e < n; e += gridDim.x) {
        int2 sd = ovf[e];
        float coef = isd[sd.x] * isd[sd.y];
        atomicAdd(&out[sd.y * D_FEAT + threadIdx.x],
                  x[sd.x * D_FEAT + threadIdx.x] * coef);
    }
}

// ---- fallback (ws too small even for buckets): round-1 atomic scatter ----
__global__ void fb_degree_kernel(const int* __restrict__ src,
                                 float* __restrict__ deg, int E) {
    int i = blockIdx.x * blockDim.x + threadIdx.x;
    if (i < E) atomicAdd(&deg[src[i]], 1.0f);
}
__global__ void fb_inv_sqrt_kernel(float* __restrict__ deg, int N) {
    int i = blockIdx.x * blockDim.x + threadIdx.x;
    if (i < N) deg[i] = rsqrtf(fmaxf(deg[i], 1.0f));
}
__global__ void fb_scatter_kernel(const float* __restrict__ x,
                                  const int* __restrict__ src,
                                  const int* __restrict__ dst,
                                  const float* __restrict__ isd,
                                  float* __restrict__ out, int E) {
    int e = blockIdx.x;
    if (e >= E) return;
    int f = threadIdx.x;
    int s = src[e], d = dst[e];
    float coef = isd[s] * isd[d];
    atomicAdd(&out[(long)d * D_FEAT + f], x[(long)s * D_FEAT + f] * coef);
}

extern "C" void kernel_launch(void* const* d_in, const int* in_sizes, int n_in,
                              void* d_out, int out_size, void* d_ws, size_t ws_size,
                              hipStream_t stream) {
    const float* x   = (const float*)d_in[0];
    const int*   src = (const int*)d_in[1];
    const int*   dst = (const int*)d_in[2];
    float* out = (float*)d_out;

    int N = in_sizes[0] / D_FEAT;   // 100000
    int E = in_sizes[1];            // 1600000

    size_t off_deg    = 0;
    size_t off_cnt    = off_deg + (size_t)N * 4;
    size_t off_isd    = off_cnt + (size_t)N * 4;
    size_t off_novf   = off_isd + (size_t)N * 4;
    size_t off_bucket = off_novf + 16;
    size_t off_ovf    = off_bucket + (size_t)N * CAP * 4;
    size_t off_xs     = off_ovf + (size_t)E * 8;
    size_t need_base  = off_xs;                       // without xs
    size_t need_xs    = off_xs + (size_t)N * D_FEAT * 4;

    if (ws_size < need_base) {
        float* deg = (float*)d_ws;
        (void)hipMemsetAsync(deg, 0, (size_t)N * sizeof(float), stream);
        (void)hipMemsetAsync(out, 0, (size_t)out_size * sizeof(float), stream);
        fb_degree_kernel<<<(E + 255) / 256, 256, 0, stream>>>(src, deg, E);
        fb_inv_sqrt_kernel<<<(N + 255) / 256, 256, 0, stream>>>(deg, N);
        fb_scatter_kernel<<<E, D_FEAT, 0, stream>>>(x, src, dst, deg, out, E);
        return;
    }

    char* ws = (char*)d_ws;
    int*   deg    = (int*)(ws + off_deg);
    int*   cnt    = (int*)(ws + off_cnt);
    float* isd    = (float*)(ws + off_isd);
    int*   novf   = (int*)(ws + off_novf);
    int*   bucket = (int*)(ws + off_bucket);
    int2*  ovf    = (int2*)(ws + off_ovf);
    float* xs     = (float*)(ws + off_xs);

    (void)hipMemsetAsync(ws, 0, off_novf + 16, stream);  // deg, cnt, isd, novf

    int sliceSz = (N + NSLICES - 1) / NSLICES;
    build_kernel<<<NSLICES * BPS, 256, 0, stream>>>(src, dst, deg, cnt,
                                                    bucket, ovf, novf, E, sliceSz);
    isd_kernel<<<(N + 255) / 256, 256, 0, stream>>>(deg, isd, N);

    int gatherGrid = (N + NODES_PER_BLOCK - 1) / NODES_PER_BLOCK;
    if (ws_size >= need_xs) {
        int n4 = N * (D_FEAT / 4);
        prescale_kernel<<<(n4 + 255) / 256, 256, 0, stream>>>(
            (const vfloat4*)x, isd, (vfloat4*)xs, n4);
        gather_kernel<<<gatherGrid, 256, 0, stream>>>(
            (const vfloat4*)xs, cnt, bucket, isd, (vfloat4*)out, N);
        overflow_kernel<<<64, D_FEAT, 0, stream>>>(xs, isd, ovf, novf, out);
    } else {
        gather_kernel_noprescale<<<gatherGrid, 256, 0, stream>>>(
            (const vfloat4*)x, cnt, bucket, isd, (vfloat4*)out, N);
        overflow_kernel_noprescale<<<64, D_FEAT, 0, stream>>>(x, isd, ovf, novf, out);
    }
}